// Round 4
// baseline (5621.289 us; speedup 1.0000x reference)
//
#include <hip/hip_runtime.h>
#include <hip/hip_bf16.h>
#include <math.h>

#define BATCH 2048
#define SEQ   80
#define EMBD  100
#define HU    512
#define NG    2048   // 4*HU
#define NBLK  256

typedef short bf16x8 __attribute__((ext_vector_type(8)));
typedef float f32x4  __attribute__((ext_vector_type(4)));

#define AS1(p) ((const __attribute__((address_space(1))) void*)(p))
#define AS3(p) ((__attribute__((address_space(3))) void*)(p))

// ---------------- prep kernels (once per call, deterministic) ----------------

// emb fp32 [10000][100] -> embp bf16 [10000][128] (cols 100..127 zero)
__global__ __launch_bounds__(256) void prep_emb(const float* __restrict__ emb,
                                                __hip_bfloat16* __restrict__ embp)
{
    int idx = blockIdx.x*256 + threadIdx.x;
    int row = idx >> 7, k = idx & 127;
    float v = (k < EMBD) ? emb[row*EMBD + k] : 0.f;
    embp[idx] = __float2bfloat16(v);
}

// Gate-interleaved transposed weights. n = u*4 + g, col_orig = g*512 + u.
__global__ __launch_bounds__(256) void prep_wt(
    const float* __restrict__ W1, const float* __restrict__ U1, const float* __restrict__ b1,
    const float* __restrict__ W2, const float* __restrict__ U2, const float* __restrict__ b2,
    __hip_bfloat16* __restrict__ wt1, __hip_bfloat16* __restrict__ wt2,
    float* __restrict__ bp1, float* __restrict__ bp2)
{
    const int n = blockIdx.x;
    const int u = n >> 2, g = n & 3, col = g*HU + u;
    if (blockIdx.y == 0) {
        for (int k = threadIdx.x; k < 640; k += 256) {
            float v = (k < EMBD) ? W1[k*NG + col] : ((k < 128) ? 0.f : U1[(k-128)*NG + col]);
            wt1[n*640 + k] = __float2bfloat16(v);
        }
        if (threadIdx.x == 0) bp1[n] = b1[col];
    } else {
        for (int k = threadIdx.x; k < 1024; k += 256) {
            float v = (k < HU) ? W2[k*NG + col] : U2[(k-HU)*NG + col];
            wt2[n*1024 + k] = __float2bfloat16(v);
        }
        if (threadIdx.x == 0) bp2[n] = b2[col];
    }
}

// ---------------- device-scope grid barrier (256 co-resident blocks) ----------------
__device__ __forceinline__ void gbar(unsigned* cnt, unsigned* gen)
{
    __syncthreads();
    if (threadIdx.x == 0) {
        __threadfence();   // release: make this block's h writes visible device-wide
        unsigned g = __hip_atomic_load(gen, __ATOMIC_RELAXED, __HIP_MEMORY_SCOPE_AGENT);
        unsigned a = __hip_atomic_fetch_add(cnt, 1u, __ATOMIC_ACQ_REL, __HIP_MEMORY_SCOPE_AGENT);
        if (a == NBLK - 1u) {
            __hip_atomic_store(cnt, 0u, __ATOMIC_RELAXED, __HIP_MEMORY_SCOPE_AGENT);
            __hip_atomic_fetch_add(gen, 1u, __ATOMIC_ACQ_REL, __HIP_MEMORY_SCOPE_AGENT);
        } else {
            while (__hip_atomic_load(gen, __ATOMIC_RELAXED, __HIP_MEMORY_SCOPE_AGENT) == g)
                __builtin_amdgcn_s_sleep(2);
        }
        __threadfence();   // acquire: invalidate stale cached h before next round's reads
    }
    __syncthreads();
}

// ---------------- one LSTM layer step for this block's 128x128 slice ----------------
// z = [x,h] @ wt^T + b -> gates -> c (LDS), h (global). 8 waves of 32x64, BK=64, dbuf.
template<int KTOT, int K1P, bool GATHER>
__device__ __forceinline__ void layer_step(
    const int* __restrict__ ids, const int t,
    const __hip_bfloat16* __restrict__ xs,     // embp (GATHER) or h1 current
    const __hip_bfloat16* __restrict__ hprev,
    const __hip_bfloat16* __restrict__ wt,     // [2048][KTOT] gate-interleaved
    const float* __restrict__ bp,
    float* __restrict__ csl,                   // LDS cell slice [128*33]
    __hip_bfloat16* __restrict__ hout,
    unsigned short* As0, unsigned short* As1,
    unsigned short* Bs0, unsigned short* Bs1,
    const int m0, const int n0)
{
    const int tid  = threadIdx.x;
    const int w    = tid >> 6;
    const int lane = tid & 63;
    const int wM   = w >> 1;
    const int wN   = w & 1;

    const int rA = lane & 15;
    const int tq = lane >> 4;
    const int rowA = m0 + w*16 + rA;
    const int rowB = n0 + w*16 + rA;

    const __hip_bfloat16* bx = GATHER ? (xs + (size_t)ids[rowA*SEQ + t]*128)
                                      : (xs + (size_t)rowA*HU);

    f32x4 acc[2][4];
    #pragma unroll
    for (int mi = 0; mi < 2; ++mi)
        #pragma unroll
        for (int ni = 0; ni < 4; ++ni)
            acc[mi][ni] = (f32x4){0.f,0.f,0.f,0.f};

    auto stage = [&](int kt, int buf){
        unsigned short* Ad = (buf ? As1 : As0) + w*1024;
        unsigned short* Bd = (buf ? Bs1 : Bs0) + w*1024;
        const int k0 = kt * 64;
        #pragma unroll
        for (int j = 0; j < 2; ++j) {
            const int kk = k0 + (j*4 + tq)*8;   // region uniform per kt (K1P%64==0)
            const __hip_bfloat16* gpA = (kk < K1P)
                ? (bx + kk)
                : (hprev + (size_t)rowA*HU + (kk - K1P));
            __builtin_amdgcn_global_load_lds(AS1(gpA), AS3(Ad + j*512), 16, 0, 0);
            const __hip_bfloat16* gpB = wt + (size_t)rowB*KTOT + kk;
            __builtin_amdgcn_global_load_lds(AS1(gpB), AS3(Bd + j*512), 16, 0, 0);
        }
    };

    stage(0, 0);
    __syncthreads();

    constexpr int NT = KTOT / 64;
    for (int kt = 0; kt < NT; ++kt) {
        const int buf = kt & 1;
        const unsigned short* Ab = buf ? As1 : As0;
        const unsigned short* Bb = buf ? Bs1 : Bs0;
        if (kt + 1 < NT) stage(kt + 1, buf ^ 1);

        #pragma unroll
        for (int s = 0; s < 2; ++s) {
            bf16x8 aF[2], bF[4];
            #pragma unroll
            for (int mi = 0; mi < 2; ++mi)
                aF[mi] = *(const bf16x8*)&Ab[(wM*2+mi)*1024 + (s*4+tq)*128 + rA*8];
            #pragma unroll
            for (int ni = 0; ni < 4; ++ni)
                bF[ni] = *(const bf16x8*)&Bb[(wN*4+ni)*1024 + (s*4+tq)*128 + rA*8];
            #pragma unroll
            for (int mi = 0; mi < 2; ++mi)
                #pragma unroll
                for (int ni = 0; ni < 4; ++ni)
                    acc[mi][ni] = __builtin_amdgcn_mfma_f32_16x16x32_bf16(aF[mi], bF[ni], acc[mi][ni], 0, 0, 0);
        }
        __syncthreads();
    }

    // Fused gate epilogue: 4-lane group = {i,f,g,o} of one unit; c in LDS (block-private).
    const int gq = lane & 3;
    const bool isT = (gq == 2);
    #pragma unroll
    for (int ni = 0; ni < 4; ++ni) {
        const int nl = wN*64 + ni*16 + (lane & 15);
        const int n  = n0 + nl;
        const float bv = bp[n];
        const int ug  = n >> 2;      // global unit
        const int ul  = nl >> 2;     // local unit 0..31
        #pragma unroll
        for (int mi = 0; mi < 2; ++mi) {
            #pragma unroll
            for (int rr = 0; rr < 4; ++rr) {
                const int rowl = wM*32 + mi*16 + (lane >> 4)*4 + rr;
                const float z  = acc[mi][ni][rr] + bv;
                const float zz = isT ? 2.f*z : z;
                const float sg = 1.f/(1.f + __expf(-zz));
                const float act = isT ? fmaf(2.f, sg, -1.f) : sg;   // tanh via sigmoid
                const float act2 = __shfl_xor(act, 2);   // i<->g, f<->o
                const float pig  = act * act2;           // gq0: sig(i)*tanh(g)
                const float pig1 = __shfl_xor(pig, 1);   // gq1 <- gq0
                const float c_old = csl[rowl*33 + ul];   // broadcast within group
                const float cn  = fmaf(act, c_old, pig1);            // gq1: sig(f)*c + i*g
                const float tcn = fmaf(2.f, 1.f/(1.f + __expf(-2.f*cn)), -1.f);
                const float tcn2 = __shfl_xor(tcn, 2);   // gq3 <- gq1
                const float hv  = act * tcn2;            // gq3: sig(o)*tanh(c)
                if (gq == 1) csl[rowl*33 + ul] = cn;
                else if (gq == 3) hout[(size_t)(m0 + rowl)*HU + ug] = __float2bfloat16(hv);
            }
        }
    }
}

// ---------------- persistent kernel: all 80 steps, 1 grid barrier per round ----------------
__global__ __launch_bounds__(512, 2) void lstm_persist(
    const int* __restrict__ ids,
    const __hip_bfloat16* __restrict__ embp,
    const __hip_bfloat16* __restrict__ wt1, const float* __restrict__ bp1,
    const __hip_bfloat16* __restrict__ wt2, const float* __restrict__ bp2,
    __hip_bfloat16* h1a, __hip_bfloat16* h1b,
    __hip_bfloat16* h2a, __hip_bfloat16* h2b,
    unsigned* cnt, unsigned* gen)
{
    __shared__ unsigned short As[2][8192];   // 32 KB
    __shared__ unsigned short Bs[2][8192];   // 32 KB
    __shared__ float cs1[128*33];            // 16.9 KB  (pad 33 breaks bank aliasing)
    __shared__ float cs2[128*33];

    // XCD-aware slice mapping (XCD = bid % 8 round-robin): each XCD hosts
    // u-slices {2x, 2x+1} for all row-blocks -> 832 KB weights L2-resident.
    const int bid = blockIdx.x;
    const int uB  = (bid & 7)*2 + ((bid >> 3) & 1);
    const int rB  = bid >> 4;
    const int m0  = rB * 128;
    const int n0  = uB * 128;

    for (int i = threadIdx.x; i < 128*33; i += 512) { cs1[i] = 0.f; cs2[i] = 0.f; }
    // (first __syncthreads inside layer_step orders this before any cs read)

    for (int r = 0; r <= SEQ; ++r) {
        const int ip = (r - 1) & 1;
        const int ic = r & 1;
        const __hip_bfloat16* h1p = ip ? h1b : h1a;   // h1_out[r-1]
        __hip_bfloat16*       h1c = ic ? h1b : h1a;   // h1_out[r]
        const __hip_bfloat16* h2c = ic ? h2b : h2a;   // h2_out[r-2]
        __hip_bfloat16*       h2p = ip ? h2b : h2a;   // h2_out[r-1]

        if (r < SEQ)
            layer_step<640,128,true>(ids, r, embp, h1p, wt1, bp1, cs1, h1c,
                                     &As[0][0], &As[1][0], &Bs[0][0], &Bs[1][0], m0, n0);
        if (r >= 1)
            layer_step<1024,512,false>(nullptr, 0, h1p, h2c, wt2, bp2, cs2, h2p,
                                     &As[0][0], &As[1][0], &Bs[0][0], &Bs[1][0], m0, n0);
        gbar(cnt, gen);
    }
}

// out[b] = sigmoid(h2[b,:] @ Wd + bd)
__global__ __launch_bounds__(256) void head_k(const __hip_bfloat16* __restrict__ h2,
    const float* __restrict__ Wd, const float* __restrict__ bd, float* __restrict__ out)
{
    const int b = blockIdx.x*4 + (threadIdx.x >> 6);
    const int lane = threadIdx.x & 63;
    float s = 0.f;
    #pragma unroll
    for (int u = lane; u < HU; u += 64) s += __bfloat162float(h2[b*HU + u]) * Wd[u];
    #pragma unroll
    for (int off = 32; off > 0; off >>= 1) s += __shfl_xor(s, off);
    if (lane == 0) out[b] = 1.f/(1.f + __expf(-(s + bd[0])));
}

extern "C" void kernel_launch(void* const* d_in, const int* in_sizes, int n_in,
                              void* d_out, int out_size, void* d_ws, size_t ws_size,
                              hipStream_t stream)
{
    const int*   ids = (const int*)  d_in[0];
    const float* emb = (const float*)d_in[1];
    const float* W1  = (const float*)d_in[2];
    const float* U1  = (const float*)d_in[3];
    const float* b1  = (const float*)d_in[4];
    const float* W2  = (const float*)d_in[5];
    const float* U2  = (const float*)d_in[6];
    const float* b2  = (const float*)d_in[7];
    const float* Wd  = (const float*)d_in[8];
    const float* bd  = (const float*)d_in[9];
    float* out = (float*)d_out;

    const size_t HS = (size_t)BATCH*HU;
    char* p = (char*)d_ws;
    unsigned* bar = (unsigned*)p;                    p += 256;   // [cnt, gen]
    __hip_bfloat16* h1a = (__hip_bfloat16*)p;        p += HS*2;
    __hip_bfloat16* h1b = (__hip_bfloat16*)p;        p += HS*2;
    __hip_bfloat16* h2a = (__hip_bfloat16*)p;        p += HS*2;
    __hip_bfloat16* h2b = (__hip_bfloat16*)p;        p += HS*2;
    __hip_bfloat16* embp = (__hip_bfloat16*)p;       p += (size_t)10000*128*2;
    __hip_bfloat16* wt1  = (__hip_bfloat16*)p;       p += (size_t)2048*640*2;
    __hip_bfloat16* wt2  = (__hip_bfloat16*)p;       p += (size_t)2048*1024*2;
    float* bp1 = (float*)p;                          p += 2048*4;
    float* bp2 = (float*)p;                          p += 2048*4;

    // zero barrier vars + all h buffers each call (deterministic)
    hipMemsetAsync(d_ws, 0, 256 + 4*HS*2, stream);

    prep_emb<<<10000*128/256, 256, 0, stream>>>(emb, embp);
    prep_wt<<<dim3(2048,2), 256, 0, stream>>>(W1,U1,b1,W2,U2,b2, wt1,wt2,bp1,bp2);

    lstm_persist<<<NBLK, 512, 0, stream>>>(ids, embp, wt1, bp1, wt2, bp2,
                                           h1a, h1b, h2a, h2b, &bar[0], &bar[1]);

    // final h2_out[79] lives in h2b ( (79)&1 == 1 )
    head_k<<<BATCH/4, 256, 0, stream>>>(h2b, Wd, bd, out);
}